// Round 9
// baseline (16040.623 us; speedup 1.0000x reference)
//
#include <hip/hip_runtime.h>
#include <math.h>

#define NN 1024
#define PP 20
#define LPC 16                 // columns per lane (64 x 16 = 1024)
#define SCALE_D 33554432.0     // 2^25
#define INV_SCALE_F (1.0f / 33554432.0f)
#define IMAX 0x7fffffff
#define ARR_CAP 4096           // continuous-ARR step cap (termination guard)

// ============ INSTRUMENTATION ROUND 2 ============
// Algorithm identical to R7 (9.87 ms steady). Phase-3 wall time is measured
// with s_memrealtime and replayed once as a busy-wait at kernel end:
//   phase3_time_us ~= dur_us(steady) - 9870
// (R8 decode gave pops3 ~= 8.8K, far below the latency-model expectation;
//  this round splits total time into phase3 vs rest, calibration-free.)
// =================================================

// ---------- cost: replicate reference fp32 op order exactly ----------
__device__ __forceinline__ float cost_ij(const float* __restrict__ a,
                                         const float* __restrict__ b) {
#pragma clang fp contract(off)
  float s = 0.0f;
#pragma unroll
  for (int p = 0; p < PP; ++p) {
    float dx = a[2 * p]     - b[2 * p];
    float dy = a[2 * p + 1] - b[2 * p + 1];
    s += sqrtf(dx * dx + dy * dy);
  }
  return s / 20.0f;
}

// Quantized cost: c * 2^25 is an exact integer for all entries in [2^-2, 2^3]
// (fp32 ulp <= 2^-25 there). Computed in double => exact product + exact cast.
__global__ void cost_kernel(const float* __restrict__ pred,
                            const float* __restrict__ gt,
                            int* __restrict__ ci) {
  int id = blockIdx.x * blockDim.x + threadIdx.x;  // 0 .. NN*NN-1
  int i = id >> 10;
  int j = id & (NN - 1);
  float c = cost_ij(pred + i * 40, gt + j * 40);
  ci[id] = (int)((double)c * SCALE_D);
}

// ---------- column minima: colv[j] = min_i ci[i][j], first argmin ----------
__global__ void colmin_kernel(const int* __restrict__ ci,
                              int* __restrict__ colv,
                              int* __restrict__ colr) {
  int j = blockIdx.x * blockDim.x + threadIdx.x;  // 1024 threads total
  int mv = ci[j];
  int mi = 0;
#pragma unroll 8
  for (int i = 1; i < NN; ++i) {
    int c = ci[i * NN + j];
    if (c < mv) { mv = c; mi = i; }
  }
  colv[j] = mv;
  colr[j] = mi;
}

// ---------- per-row top-2 reduced costs vs v0 (for reduction transfer) ----
__global__ __launch_bounds__(64) void rowmin_kernel(
    const int* __restrict__ ci, const int* __restrict__ colv,
    int* __restrict__ rm1, int* __restrict__ rm2, int* __restrict__ rj1) {
  const int row = blockIdx.x;
  const int lane = threadIdx.x;
  const int* cr = ci + (size_t)row * NN + lane * LPC;
  const int* vr = colv + lane * LPC;
  int4 ca = ((const int4*)cr)[0], cb = ((const int4*)cr)[1],
       cc = ((const int4*)cr)[2], cd = ((const int4*)cr)[3];
  int4 va = ((const int4*)vr)[0], vb = ((const int4*)vr)[1],
       vc = ((const int4*)vr)[2], vd = ((const int4*)vr)[3];
  int c[LPC] = {ca.x, ca.y, ca.z, ca.w, cb.x, cb.y, cb.z, cb.w,
                cc.x, cc.y, cc.z, cc.w, cd.x, cd.y, cd.z, cd.w};
  int v[LPC] = {va.x, va.y, va.z, va.w, vb.x, vb.y, vb.z, vb.w,
                vc.x, vc.y, vc.z, vc.w, vd.x, vd.y, vd.z, vd.w};
  int m1 = IMAX, m2 = IMAX, c1 = IMAX;
#pragma unroll
  for (int q = 0; q < LPC; ++q) {
    const int d = c[q] - v[q];
    if (d < m1) { m2 = m1; m1 = d; c1 = lane * LPC + q; }
    else if (d < m2) m2 = d;
  }
#pragma unroll
  for (int m = 1; m < 64; m <<= 1) {
    const int pm1 = __shfl_xor(m1, m);
    const int pm2 = __shfl_xor(m2, m);
    const int pc1 = __shfl_xor(c1, m);
    const int hi = (m1 > pm1) ? m1 : pm1;
    const int lo2 = (m2 < pm2) ? m2 : pm2;
    if (pm1 < m1 || (pm1 == m1 && pc1 < c1)) { m1 = pm1; c1 = pc1; }
    m2 = (hi < lo2) ? hi : lo2;
  }
  if (lane == 0) { rm1[row] = m1; rm2[row] = m2; rj1[row] = c1; }
}

// ---------- wave64 min via DPP (LLVM AtomicOptimizer wave64 pattern) -------
__device__ __forceinline__ int wave_min_bcast(int x) {
  int t;
  t = __builtin_amdgcn_update_dpp(IMAX, x, 0x111, 0xf, 0xf, false);  // row_shr:1
  x = (t < x) ? t : x;
  t = __builtin_amdgcn_update_dpp(IMAX, x, 0x112, 0xf, 0xf, false);  // row_shr:2
  x = (t < x) ? t : x;
  t = __builtin_amdgcn_update_dpp(IMAX, x, 0x114, 0xf, 0xf, false);  // row_shr:4
  x = (t < x) ? t : x;
  t = __builtin_amdgcn_update_dpp(IMAX, x, 0x118, 0xf, 0xf, false);  // row_shr:8
  x = (t < x) ? t : x;
  t = __builtin_amdgcn_update_dpp(IMAX, x, 0x142, 0xf, 0xf, false);  // row_bcast:15
  x = (t < x) ? t : x;
  t = __builtin_amdgcn_update_dpp(IMAX, x, 0x143, 0xf, 0xf, false);  // row_bcast:31
  x = (t < x) ? t : x;
  return __builtin_amdgcn_readlane(x, 63);
}

// ---------- integer JV: greedy + RT + continuous ARR + Dijkstra ----------
__global__ __launch_bounds__(64) void lap_kernel(
    const float* __restrict__ gt, const int* __restrict__ ci,
    const int* __restrict__ colv, const int* __restrict__ colr,
    const int* __restrict__ rm1, const int* __restrict__ rm2,
    const int* __restrict__ rj1, float* __restrict__ out) {
  const int lane = threadIdx.x;

  __shared__ int u_s[NN];
  __shared__ int row4col_s[NN];
  __shared__ int col4row_s[NN];
  __shared__ int path_s[NN];
  __shared__ int queue_s[NN + ARR_CAP];  // displacement ring (head..tail)

  int nv_r[LPC];  // NEGATED v duals for owned cols (enables v_add3 relax)
  int sh_r[LPC];  // Dijkstra labels (keep settle value after settling)
  int kq_r[LPC];  // argmin key: == sh_r while active, IMAX when settled
  int pa_r[LPC];  // predecessor row per owned col
  int rc_r[LPC];  // register mirror of row4col for owned cols

  // ---- L2 priming: stream the 4 MB cost matrix into this CU's XCD L2 ----
  {
    const int4* p4 = (const int4*)ci;
    int ax = 0, ay = 0, az = 0, aw = 0;
    for (int it = 0; it < (NN * NN / 4) / 64; it += 8) {
#pragma unroll
      for (int uu = 0; uu < 8; ++uu) {
        const int4 tv = p4[(size_t)(it + uu) * 64 + lane];
        ax ^= tv.x; ay ^= tv.y; az ^= tv.z; aw ^= tv.w;
      }
    }
    asm volatile("" :: "v"(ax), "v"(ay), "v"(az), "v"(aw));  // keep loads live
  }

#pragma unroll
  for (int q = 0; q < LPC; ++q) {
    const int j = lane * LPC + q;
    u_s[j] = 0;
    row4col_s[j] = -1;
    col4row_s[j] = -1;
  }
  __syncthreads();

  // ---- phase 1: greedy claim via column argmins (serial, deterministic) ----
  if (lane == 0) {
    for (int j = 0; j < NN; ++j) {
      const int i = colr[j];
      if (col4row_s[i] < 0) { col4row_s[i] = j; row4col_s[j] = i; }
    }
  }
  __syncthreads();

  // ---- reduction transfer (Jacobi-parallel, integer-exact feasible) ----
#pragma unroll
  for (int q = 0; q < LPC; ++q) {
    const int j = lane * LPC + q;
    const int i = row4col_s[j];
    int nvv = -colv[j];
    if (i >= 0) {
      const int mu = (rj1[i] == j) ? rm2[i] : rm1[i];
      u_s[i] = mu;  // injective (row4col is injective)
      nvv += mu;
    }
    nv_r[q] = nvv;
  }
  if (lane == 0) {
    int n = 0;
    for (int i = 0; i < NN; ++i)
      if (col4row_s[i] < 0) queue_s[n++] = i;
    path_s[0] = n;  // temp: initial free count
  }
  __syncthreads();
  int head = 0;
  int tail = path_s[0];  // uniform
  __syncthreads();

  // ---- phase 2: continuous augmenting row reduction (JV87 queue) ----
  for (int step = 0; step < ARR_CAP && head < tail; ++step) {
    const int i = queue_s[head];  // uniform read
    ++head;
    const int* cr = ci + (size_t)i * NN + lane * LPC;
    int4 ca = ((const int4*)cr)[0], cb = ((const int4*)cr)[1],
         cc = ((const int4*)cr)[2], cd = ((const int4*)cr)[3];
    int c[LPC] = {ca.x, ca.y, ca.z, ca.w, cb.x, cb.y, cb.z, cb.w,
                  cc.x, cc.y, cc.z, cc.w, cd.x, cd.y, cd.z, cd.w};
    int m1 = IMAX, m2 = IMAX, c1 = 0;
#pragma unroll
    for (int q = 0; q < LPC; ++q) {
      const int d = c[q] + nv_r[q];
      if (d < m1) { m2 = m1; m1 = d; c1 = q; }
      else if (d < m2) m2 = d;
    }
    // cross-lane via DPP min + ballot (lowest lane = lowest col)
    const int m1g = wave_min_bcast(m1);
    const unsigned long long ball = __ballot(m1 == m1g);
    const int wl = __ffsll(ball) - 1;
    const int cand = (lane == wl) ? m2 : m1;  // drop one winning element
    const int m2g = wave_min_bcast(cand);
    const int j1 = (wl << 4) | __builtin_amdgcn_readlane(c1, wl);
    const int delta = m2g - m1g;  // >= 0
    if (lane == wl && delta > 0) {
#pragma unroll
      for (int q = 0; q < LPC; ++q)
        if (q == (j1 & 15)) nv_r[q] += delta;  // v[j1] = c[i][j1] - m2g
    }
    const int k = row4col_s[j1];  // pre-write value (fenced by barriers)
    __syncthreads();
    if (lane == 0) {
      u_s[i] = m2g;
      row4col_s[j1] = i;
      col4row_s[i] = j1;
      if (k >= 0) {
        col4row_s[k] = -1;
        queue_s[tail] = k;
      }
    }
    if (k >= 0) ++tail;  // uniform (k from uniform LDS read)
    __syncthreads();
  }

#pragma unroll
  for (int q = 0; q < LPC; ++q) rc_r[q] = row4col_s[lane * LPC + q];
  __syncthreads();

  // ---- phase 3: integer Dijkstra augmentation (TIMED with s_memrealtime) --
  const unsigned long long t0 = __builtin_amdgcn_s_memrealtime();
  const int nfree = tail - head;
  for (int fi = 0; fi < nfree; ++fi) {
    const int r = queue_s[head + fi];  // uniform
#pragma unroll
    for (int q = 0; q < LPC; ++q) { sh_r[q] = IMAX; kq_r[q] = IMAX; }
    int i = r;
    int mv = 0;
    int A = __builtin_amdgcn_readfirstlane(-u_s[r]);  // A = mv - u_i (SGPR)
    int sink;
    while (true) {
      const int* cr = ci + (size_t)i * NN + lane * LPC;
      int4 ca = ((const int4*)cr)[0], cb = ((const int4*)cr)[1],
           cc = ((const int4*)cr)[2], cd = ((const int4*)cr)[3];
      int c[LPC] = {ca.x, ca.y, ca.z, ca.w, cb.x, cb.y, cb.z, cb.w,
                    cc.x, cc.y, cc.z, cc.w, cd.x, cd.y, cd.z, cd.w};
      // relax: d = A + c + nv  (v_add3, one SGPR operand)
#pragma unroll
      for (int q = 0; q < LPC; ++q) {
        const int d = A + c[q] + nv_r[q];
        const bool upd = d < sh_r[q];
        sh_r[q] = upd ? d : sh_r[q];
        kq_r[q] = upd ? d : kq_r[q];
        pa_r[q] = upd ? i : pa_r[q];
      }
      // in-lane argmin tree on kq (strict < keeps lowest q), carrying (q, rc)
      int t1k[8], t1e[8], t1r[8];
#pragma unroll
      for (int q = 0; q < 8; ++q) {
        const bool b = kq_r[2 * q + 1] < kq_r[2 * q];
        t1k[q] = b ? kq_r[2 * q + 1] : kq_r[2 * q];
        t1e[q] = b ? 2 * q + 1 : 2 * q;
        t1r[q] = b ? rc_r[2 * q + 1] : rc_r[2 * q];
      }
      int t2k[4], t2e[4], t2r[4];
#pragma unroll
      for (int q = 0; q < 4; ++q) {
        const bool b = t1k[2 * q + 1] < t1k[2 * q];
        t2k[q] = b ? t1k[2 * q + 1] : t1k[2 * q];
        t2e[q] = b ? t1e[2 * q + 1] : t1e[2 * q];
        t2r[q] = b ? t1r[2 * q + 1] : t1r[2 * q];
      }
      int t3k[2], t3e[2], t3r[2];
#pragma unroll
      for (int q = 0; q < 2; ++q) {
        const bool b = t2k[2 * q + 1] < t2k[2 * q];
        t3k[q] = b ? t2k[2 * q + 1] : t2k[2 * q];
        t3e[q] = b ? t2e[2 * q + 1] : t2e[2 * q];
        t3r[q] = b ? t2r[2 * q + 1] : t2r[2 * q];
      }
      const bool b0 = t3k[1] < t3k[0];
      const int bs = b0 ? t3k[1] : t3k[0];
      const int bq = b0 ? t3e[1] : t3e[0];
      const int brc = b0 ? t3r[1] : t3r[0];
      // cross-lane: DPP min + ballot winner (lowest lane = lowest col)
      const int minkey = wave_min_bcast(bs);
      const unsigned long long ball = __ballot(bs == minkey);
      const int wl = __ffsll(ball) - 1;
      const int kcol = (wl << 4) | __builtin_amdgcn_readlane(bq, wl);
      const int krc = __builtin_amdgcn_readlane(brc, wl);
      mv = minkey;
      if (krc < 0) { sink = kcol; break; }
      if (lane == (kcol >> 4)) {  // settle kcol: remove from argmin domain
#pragma unroll
        for (int q = 0; q < LPC; ++q)
          if (q == (kcol & 15)) kq_r[q] = IMAX;
      }
      i = krc;
      A = __builtin_amdgcn_readfirstlane(mv - u_s[i]);  // hidden under row load
    }
    // dual updates: settled <=> kq==IMAX && sh<IMAX (sink excluded: delta 0)
#pragma unroll
    for (int q = 0; q < LPC; ++q) {
      if (kq_r[q] == IMAX && sh_r[q] != IMAX) {
        const int delta = mv - sh_r[q];
        const int i2 = rc_r[q];
        if (i2 >= 0) u_s[i2] += delta;  // injective addresses
        nv_r[q] += delta;               // v -= delta
      }
      path_s[lane * LPC + q] = pa_r[q];
    }
    if (lane == 0) u_s[r] += mv;
    __syncthreads();
    if (lane == 0) {
      int j = sink;
      while (true) {
        const int i2 = path_s[j];
        row4col_s[j] = i2;
        const int jn = col4row_s[i2];
        col4row_s[i2] = j;
        j = jn;
        if (i2 == r) break;
      }
    }
    __syncthreads();
#pragma unroll
    for (int q = 0; q < LPC; ++q) rc_r[q] = row4col_s[lane * LPC + q];
  }
  __syncthreads();
  const unsigned long long t1 = __builtin_amdgcn_s_memrealtime();
  const unsigned long long dt3 = t1 - t0;  // phase-3 wall ticks

  // ---------- outputs: 16 rows per lane ----------
#pragma unroll
  for (int q = 0; q < LPC; ++q) {
    const int row = lane * LPC + q;
    const int col = col4row_s[row];
    const float4* g4 = (const float4*)(gt + (size_t)col * 40);
    float4* o4 = (float4*)(out + (size_t)row * 40);
#pragma unroll
    for (int w = 0; w < 10; ++w) o4[w] = g4[w];
    // exact fp32 recovery: ci has <=24 significant bits, scale is pow2
    const float cf = (float)ci[(size_t)row * NN + col] * INV_SCALE_F;
    out[NN * 40 + row] = expf(-cf);
  }

  // ---- instrumentation: replay phase-3 duration once (same clock) ----
  // decode: phase3_us ~= dur_us(steady) - 9870
  const unsigned long long t2 = __builtin_amdgcn_s_memrealtime();
  while (__builtin_amdgcn_s_memrealtime() - t2 < dt3)
    asm volatile("s_sleep 1");
}

extern "C" void kernel_launch(void* const* d_in, const int* in_sizes, int n_in,
                              void* d_out, int out_size, void* d_ws,
                              size_t ws_size, hipStream_t stream) {
  const float* pred = (const float*)d_in[0];
  const float* gt = (const float*)d_in[1];
  float* out = (float*)d_out;
  int* ci = (int*)d_ws;  // 4 MB quantized cost

  // scratch in d_out's first 20 KB; every element overwritten by lap epilogue
  int* colv = (int*)out;
  int* colr = colv + NN;
  int* rm1 = colr + NN;
  int* rm2 = rm1 + NN;
  int* rj1 = rm2 + NN;

  cost_kernel<<<NN * NN / 256, 256, 0, stream>>>(pred, gt, ci);
  colmin_kernel<<<NN / 256, 256, 0, stream>>>(ci, colv, colr);
  rowmin_kernel<<<NN, 64, 0, stream>>>(ci, colv, rm1, rm2, rj1);
  lap_kernel<<<1, 64, 0, stream>>>(gt, ci, colv, colr, rm1, rm2, rj1, out);
}

// Round 10
// 14888.643 us; speedup vs baseline: 1.0774x; 1.0774x over previous
//
#include <hip/hip_runtime.h>
#include <math.h>

#define NN 1024
#define PP 20
#define LPC 16                 // columns per lane (64 x 16 = 1024)
#define SCALE_D 33554432.0     // 2^25
#define INV_SCALE_F (1.0f / 33554432.0f)
#define IMAX 0x7fffffff
#define ARR_CAP 4096           // continuous-ARR step cap (termination guard)

// ---------- cost: replicate reference fp32 op order exactly ----------
__device__ __forceinline__ float cost_ij(const float* __restrict__ a,
                                         const float* __restrict__ b) {
#pragma clang fp contract(off)
  float s = 0.0f;
#pragma unroll
  for (int p = 0; p < PP; ++p) {
    float dx = a[2 * p]     - b[2 * p];
    float dy = a[2 * p + 1] - b[2 * p + 1];
    s += sqrtf(dx * dx + dy * dy);
  }
  return s / 20.0f;
}

// Quantized cost: c * 2^25 is an exact integer for all entries in [2^-2, 2^3]
// (fp32 ulp <= 2^-25 there). Computed in double => exact product + exact cast.
__global__ void cost_kernel(const float* __restrict__ pred,
                            const float* __restrict__ gt,
                            int* __restrict__ ci) {
  int id = blockIdx.x * blockDim.x + threadIdx.x;  // 0 .. NN*NN-1
  int i = id >> 10;
  int j = id & (NN - 1);
  float c = cost_ij(pred + i * 40, gt + j * 40);
  ci[id] = (int)((double)c * SCALE_D);
}

// ---------- column minima: colv[j] = min_i ci[i][j], first argmin ----------
__global__ void colmin_kernel(const int* __restrict__ ci,
                              int* __restrict__ colv,
                              int* __restrict__ colr) {
  int j = blockIdx.x * blockDim.x + threadIdx.x;  // 1024 threads total
  int mv = ci[j];
  int mi = 0;
#pragma unroll 8
  for (int i = 1; i < NN; ++i) {
    int c = ci[i * NN + j];
    if (c < mv) { mv = c; mi = i; }
  }
  colv[j] = mv;
  colr[j] = mi;
}

// ---------- per-row top-2 reduced costs vs v0 (for reduction transfer) ----
__global__ __launch_bounds__(64) void rowmin_kernel(
    const int* __restrict__ ci, const int* __restrict__ colv,
    int* __restrict__ rm1, int* __restrict__ rm2, int* __restrict__ rj1) {
  const int row = blockIdx.x;
  const int lane = threadIdx.x;
  const int* cr = ci + (size_t)row * NN + lane * LPC;
  const int* vr = colv + lane * LPC;
  int4 ca = ((const int4*)cr)[0], cb = ((const int4*)cr)[1],
       cc = ((const int4*)cr)[2], cd = ((const int4*)cr)[3];
  int4 va = ((const int4*)vr)[0], vb = ((const int4*)vr)[1],
       vc = ((const int4*)vr)[2], vd = ((const int4*)vr)[3];
  int c[LPC] = {ca.x, ca.y, ca.z, ca.w, cb.x, cb.y, cb.z, cb.w,
                cc.x, cc.y, cc.z, cc.w, cd.x, cd.y, cd.z, cd.w};
  int v[LPC] = {va.x, va.y, va.z, va.w, vb.x, vb.y, vb.z, vb.w,
                vc.x, vc.y, vc.z, vc.w, vd.x, vd.y, vd.z, vd.w};
  int m1 = IMAX, m2 = IMAX, c1 = IMAX;
#pragma unroll
  for (int q = 0; q < LPC; ++q) {
    const int d = c[q] - v[q];
    if (d < m1) { m2 = m1; m1 = d; c1 = lane * LPC + q; }
    else if (d < m2) m2 = d;
  }
#pragma unroll
  for (int m = 1; m < 64; m <<= 1) {
    const int pm1 = __shfl_xor(m1, m);
    const int pm2 = __shfl_xor(m2, m);
    const int pc1 = __shfl_xor(c1, m);
    const int hi = (m1 > pm1) ? m1 : pm1;
    const int lo2 = (m2 < pm2) ? m2 : pm2;
    if (pm1 < m1 || (pm1 == m1 && pc1 < c1)) { m1 = pm1; c1 = pc1; }
    m2 = (hi < lo2) ? hi : lo2;
  }
  if (lane == 0) { rm1[row] = m1; rm2[row] = m2; rj1[row] = c1; }
}

// ---------- DPP wave64 reductions (LLVM AtomicOptimizer pattern) ----------
// row_shr 1/2/4/8 + row_bcast 15/31: each lane contributes EXACTLY ONCE to
// lane 63 (same sequence LLVM uses for non-idempotent f32 sum), so the
// pairwise top-2 merge below is exact. Result lands in lane 63.
template <int CTRL>
__device__ __forceinline__ void argmin_step(int& k, int& p) {
  const int k2 = __builtin_amdgcn_update_dpp(IMAX, k, CTRL, 0xf, 0xf, false);
  const int p2 = __builtin_amdgcn_update_dpp(0, p, CTRL, 0xf, 0xf, false);
  if (k2 < k) { k = k2; p = p2; }
}
__device__ __forceinline__ void wave_argmin(int& k, int& p) {
  argmin_step<0x111>(k, p);  // row_shr:1
  argmin_step<0x112>(k, p);  // row_shr:2
  argmin_step<0x114>(k, p);  // row_shr:4
  argmin_step<0x118>(k, p);  // row_shr:8
  argmin_step<0x142>(k, p);  // row_bcast:15
  argmin_step<0x143>(k, p);  // row_bcast:31
}
template <int CTRL>
__device__ __forceinline__ void top2_step(int& m1, int& m2, int& p1) {
  const int a1 = __builtin_amdgcn_update_dpp(IMAX, m1, CTRL, 0xf, 0xf, false);
  const int a2 = __builtin_amdgcn_update_dpp(IMAX, m2, CTRL, 0xf, 0xf, false);
  const int ap = __builtin_amdgcn_update_dpp(0, p1, CTRL, 0xf, 0xf, false);
  const int hi = m1 > a1 ? m1 : a1;
  const int lo = m2 < a2 ? m2 : a2;
  if (a1 < m1) { m1 = a1; p1 = ap; }
  m2 = hi < lo ? hi : lo;  // exact merged second-min
}
__device__ __forceinline__ void wave_top2(int& m1, int& m2, int& p1) {
  top2_step<0x111>(m1, m2, p1);
  top2_step<0x112>(m1, m2, p1);
  top2_step<0x114>(m1, m2, p1);
  top2_step<0x118>(m1, m2, p1);
  top2_step<0x142>(m1, m2, p1);
  top2_step<0x143>(m1, m2, p1);
}

// LDS-only barrier: drains lgkmcnt but leaves global prefetch loads in
// flight across the barrier (plain __syncthreads would drain vmcnt(0)).
#define LGKM_BARRIER()                                \
  do {                                                \
    asm volatile("s_waitcnt lgkmcnt(0)" ::: "memory"); \
    __builtin_amdgcn_s_barrier();                     \
  } while (0)

#define PF_ISSUE(row)                                                    \
  do {                                                                   \
    const int4* _pr = (const int4*)(ci + (size_t)(row)*NN + lane * LPC); \
    P0 = _pr[0]; P1 = _pr[1]; P2 = _pr[2]; P3 = _pr[3];                  \
  } while (0)

#define UNPACK_P(c)                                      \
  do {                                                   \
    c[0] = P0.x; c[1] = P0.y; c[2] = P0.z; c[3] = P0.w;  \
    c[4] = P1.x; c[5] = P1.y; c[6] = P1.z; c[7] = P1.w;  \
    c[8] = P2.x; c[9] = P2.y; c[10] = P2.z; c[11] = P2.w; \
    c[12] = P3.x; c[13] = P3.y; c[14] = P3.z; c[15] = P3.w; \
  } while (0)

#define LOAD_C(c, row)                                                   \
  do {                                                                   \
    const int4* _cr = (const int4*)(ci + (size_t)(row)*NN + lane * LPC); \
    const int4 _a = _cr[0], _b = _cr[1], _d = _cr[2], _e = _cr[3];       \
    c[0] = _a.x; c[1] = _a.y; c[2] = _a.z; c[3] = _a.w;                  \
    c[4] = _b.x; c[5] = _b.y; c[6] = _b.z; c[7] = _b.w;                  \
    c[8] = _d.x; c[9] = _d.y; c[10] = _d.z; c[11] = _d.w;                \
    c[12] = _e.x; c[13] = _e.y; c[14] = _e.z; c[15] = _e.w;              \
  } while (0)

// ---------- integer JV: greedy + RT + continuous ARR + Dijkstra ----------
__global__ __launch_bounds__(64) void lap_kernel(
    const float* __restrict__ gt, const int* __restrict__ ci,
    const int* __restrict__ colv, const int* __restrict__ colr,
    const int* __restrict__ rm1, const int* __restrict__ rm2,
    const int* __restrict__ rj1, float* __restrict__ out) {
  const int lane = threadIdx.x;

  __shared__ int u_s[NN];
  __shared__ int row4col_s[NN];
  __shared__ int col4row_s[NN];
  __shared__ int path_s[NN];
  __shared__ int queue_s[NN + ARR_CAP];  // displacement ring (head..tail)

  int nv_r[LPC];   // NEGATED v duals for owned cols (v_add3 relax)
  int sh_r[LPC];   // Dijkstra labels (keep settle value after settling)
  int kq_r[LPC];   // argmin key: == sh_r while active, IMAX when settled
  int pa_r[LPC];   // predecessor row per owned col
  int prc_r[LPC];  // packed ((row4col+1)<<10)|col payload for owned cols
  int4 P0, P1, P2, P3;  // prefetched cost row
  int pf_row = -1;

  // ---- L2 priming: stream the 4 MB cost matrix into this CU's XCD L2 ----
  {
    const int4* p4 = (const int4*)ci;
    int ax = 0, ay = 0, az = 0, aw = 0;
    for (int it = 0; it < (NN * NN / 4) / 64; it += 8) {
#pragma unroll
      for (int uu = 0; uu < 8; ++uu) {
        const int4 tv = p4[(size_t)(it + uu) * 64 + lane];
        ax ^= tv.x; ay ^= tv.y; az ^= tv.z; aw ^= tv.w;
      }
    }
    asm volatile("" :: "v"(ax), "v"(ay), "v"(az), "v"(aw));  // keep loads live
  }

#pragma unroll
  for (int q = 0; q < LPC; ++q) {
    const int j = lane * LPC + q;
    u_s[j] = 0;
    row4col_s[j] = -1;
    col4row_s[j] = -1;
  }
  __syncthreads();

  // ---- phase 1: greedy claim via column argmins (serial, deterministic) ----
  if (lane == 0) {
    for (int j = 0; j < NN; ++j) {
      const int i = colr[j];
      if (col4row_s[i] < 0) { col4row_s[i] = j; row4col_s[j] = i; }
    }
  }
  __syncthreads();

  // ---- reduction transfer (Jacobi-parallel, integer-exact feasible) ----
#pragma unroll
  for (int q = 0; q < LPC; ++q) {
    const int j = lane * LPC + q;
    const int i = row4col_s[j];
    int nvv = -colv[j];
    if (i >= 0) {
      const int mu = (rj1[i] == j) ? rm2[i] : rm1[i];
      u_s[i] = mu;  // injective (row4col is injective)
      nvv += mu;
    }
    nv_r[q] = nvv;
  }
  if (lane == 0) {
    int n = 0;
    for (int i = 0; i < NN; ++i)
      if (col4row_s[i] < 0) queue_s[n++] = i;
    path_s[0] = n;  // temp: initial free count
  }
  __syncthreads();
  int head = 0;
  int tail = path_s[0];  // uniform
  __syncthreads();

  // ---- phase 2: continuous ARR (JV87 queue), prefetch-pipelined ----
  if (head < tail) { pf_row = queue_s[head]; PF_ISSUE(pf_row); }
  for (int step = 0; step < ARR_CAP && head < tail; ++step) {
    const int i = queue_s[head];  // uniform read
    ++head;
    int c[LPC];
    if (i == pf_row) { UNPACK_P(c); }
    else             { LOAD_C(c, i); }  // cold fallback (queue-empty edge)
    // prefetch next queued row; loads fly across the reduce + LDS barriers
    if (head < tail) { pf_row = queue_s[head]; PF_ISSUE(pf_row); }
    else pf_row = -1;

    int m1 = IMAX, m2 = IMAX, c1 = 0;
#pragma unroll
    for (int q = 0; q < LPC; ++q) {
      const int d = c[q] + nv_r[q];
      if (d < m1) { m2 = m1; m1 = d; c1 = q; }
      else if (d < m2) m2 = d;
    }
    int p1 = (lane << 4) | c1;
    wave_top2(m1, m2, p1);  // exact (m1, m2) + argmin col payload
    const int m1g = __builtin_amdgcn_readlane(m1, 63);
    const int m2g = __builtin_amdgcn_readlane(m2, 63);
    const int j1 = __builtin_amdgcn_readlane(p1, 63);
    const int delta = m2g - m1g;  // >= 0
    if (lane == (j1 >> 4) && delta > 0) {
#pragma unroll
      for (int q = 0; q < LPC; ++q)
        if (q == (j1 & 15)) nv_r[q] += delta;  // v[j1] = c[i][j1] - m2g
    }
    const int k = row4col_s[j1];  // pre-write value (fenced by barriers)
    LGKM_BARRIER();
    if (lane == 0) {
      u_s[i] = m2g;
      row4col_s[j1] = i;
      col4row_s[i] = j1;
      if (k >= 0) {
        col4row_s[k] = -1;
        queue_s[tail] = k;
      }
    }
    if (k >= 0) ++tail;  // uniform
    LGKM_BARRIER();
  }

#pragma unroll
  for (int q = 0; q < LPC; ++q) {
    const int rcq = row4col_s[lane * LPC + q];
    prc_r[q] = ((rcq + 1) << 10) | (lane * LPC + q);
  }
  __syncthreads();

  // ---- phase 3: integer Dijkstra augmentation for queue residual rows ----
  const int nfree = tail - head;
  pf_row = -1;
  if (nfree > 0) { pf_row = queue_s[head]; PF_ISSUE(pf_row); }
  for (int fi = 0; fi < nfree; ++fi) {
    const int r = queue_s[head + fi];  // uniform
#pragma unroll
    for (int q = 0; q < LPC; ++q) { sh_r[q] = IMAX; kq_r[q] = IMAX; }
    int i = r;
    int mv = 0;
    int A = __builtin_amdgcn_readfirstlane(-u_s[r]);  // A = mv - u_i (SGPR)
    int sink;
    while (true) {
      int c[LPC];
      if (i == pf_row) { UNPACK_P(c); }
      else             { LOAD_C(c, i); }
      pf_row = -1;  // one-shot
      // relax: d = A + c + nv (v_add3); settled cols can't improve => no mask
#pragma unroll
      for (int q = 0; q < LPC; ++q) {
        const int d = A + c[q] + nv_r[q];
        const bool upd = d < sh_r[q];
        sh_r[q] = upd ? d : sh_r[q];
        kq_r[q] = upd ? d : kq_r[q];
        pa_r[q] = upd ? i : pa_r[q];
      }
      // in-lane argmin tree over 16, carrying packed (rc, col) payload
      int a1k[8], a1p[8];
#pragma unroll
      for (int q = 0; q < 8; ++q) {
        const bool b = kq_r[2 * q + 1] < kq_r[2 * q];
        a1k[q] = b ? kq_r[2 * q + 1] : kq_r[2 * q];
        a1p[q] = b ? prc_r[2 * q + 1] : prc_r[2 * q];
      }
      int a2k[4], a2p[4];
#pragma unroll
      for (int q = 0; q < 4; ++q) {
        const bool b = a1k[2 * q + 1] < a1k[2 * q];
        a2k[q] = b ? a1k[2 * q + 1] : a1k[2 * q];
        a2p[q] = b ? a1p[2 * q + 1] : a1p[2 * q];
      }
      int a3k[2], a3p[2];
#pragma unroll
      for (int q = 0; q < 2; ++q) {
        const bool b = a2k[2 * q + 1] < a2k[2 * q];
        a3k[q] = b ? a2k[2 * q + 1] : a2k[2 * q];
        a3p[q] = b ? a2p[2 * q + 1] : a2p[2 * q];
      }
      const bool b0 = a3k[1] < a3k[0];
      int bk = b0 ? a3k[1] : a3k[0];
      int bp = b0 ? a3p[1] : a3p[0];
      // cross-lane payload-carrying DPP argmin (no ballot/ffs tail)
      wave_argmin(bk, bp);
      mv = __builtin_amdgcn_readlane(bk, 63);
      const int pk = __builtin_amdgcn_readlane(bp, 63);
      const int kcol = pk & 1023;
      const int krc = (pk >> 10) - 1;
      if (krc < 0) { sink = kcol; break; }
      if (lane == (kcol >> 4)) {  // settle kcol
#pragma unroll
        for (int q = 0; q < LPC; ++q)
          if (q == (kcol & 15)) kq_r[q] = IMAX;
      }
      i = krc;
      A = __builtin_amdgcn_readfirstlane(mv - u_s[i]);  // hidden under load
    }
    // prefetch next augmentation's first row; overlaps epilogue below
    if (fi + 1 < nfree) { pf_row = queue_s[head + fi + 1]; PF_ISSUE(pf_row); }
    // dual updates: settled <=> kq==IMAX && sh<IMAX (sink excluded: delta 0)
#pragma unroll
    for (int q = 0; q < LPC; ++q) {
      if (kq_r[q] == IMAX && sh_r[q] != IMAX) {
        const int delta = mv - sh_r[q];
        const int i2 = (prc_r[q] >> 10) - 1;
        if (i2 >= 0) u_s[i2] += delta;  // injective addresses
        nv_r[q] += delta;               // v -= delta
      }
      path_s[lane * LPC + q] = pa_r[q];
    }
    if (lane == 0) u_s[r] += mv;
    LGKM_BARRIER();
    if (lane == 0) {
      int j = sink;
      while (true) {
        const int i2 = path_s[j];
        row4col_s[j] = i2;
        const int jn = col4row_s[i2];
        col4row_s[i2] = j;
        j = jn;
        if (i2 == r) break;
      }
    }
    LGKM_BARRIER();
#pragma unroll
    for (int q = 0; q < LPC; ++q) {
      const int rcq = row4col_s[lane * LPC + q];
      prc_r[q] = ((rcq + 1) << 10) | (lane * LPC + q);
    }
  }
  __syncthreads();

  // ---------- outputs: 16 rows per lane ----------
#pragma unroll
  for (int q = 0; q < LPC; ++q) {
    const int row = lane * LPC + q;
    const int col = col4row_s[row];
    const float4* g4 = (const float4*)(gt + (size_t)col * 40);
    float4* o4 = (float4*)(out + (size_t)row * 40);
#pragma unroll
    for (int w = 0; w < 10; ++w) o4[w] = g4[w];
    // exact fp32 recovery: ci has <=24 significant bits, scale is pow2
    const float cf = (float)ci[(size_t)row * NN + col] * INV_SCALE_F;
    out[NN * 40 + row] = expf(-cf);
  }
}

extern "C" void kernel_launch(void* const* d_in, const int* in_sizes, int n_in,
                              void* d_out, int out_size, void* d_ws,
                              size_t ws_size, hipStream_t stream) {
  const float* pred = (const float*)d_in[0];
  const float* gt = (const float*)d_in[1];
  float* out = (float*)d_out;
  int* ci = (int*)d_ws;  // 4 MB quantized cost

  // scratch in d_out's first 20 KB; every element overwritten by lap epilogue
  int* colv = (int*)out;
  int* colr = colv + NN;
  int* rm1 = colr + NN;
  int* rm2 = rm1 + NN;
  int* rj1 = rm2 + NN;

  cost_kernel<<<NN * NN / 256, 256, 0, stream>>>(pred, gt, ci);
  colmin_kernel<<<NN / 256, 256, 0, stream>>>(ci, colv, colr);
  rowmin_kernel<<<NN, 64, 0, stream>>>(ci, colv, rm1, rm2, rj1);
  lap_kernel<<<1, 64, 0, stream>>>(gt, ci, colv, colr, rm1, rm2, rj1, out);
}

// Round 11
// 10025.178 us; speedup vs baseline: 1.6000x; 1.4851x over previous
//
#include <hip/hip_runtime.h>
#include <math.h>

#define NN 1024
#define PP 20
#define LPC 16                 // columns per lane (64 x 16 = 1024)
#define SCALE_D 33554432.0     // 2^25
#define INV_SCALE_F (1.0f / 33554432.0f)
#define IMAX 0x7fffffff
#define NROUNDS 20             // parallel auction rounds
#define ARR_CAP2 1536          // in-kernel residual ARR cap

// ---------- cost: replicate reference fp32 op order exactly ----------
__device__ __forceinline__ float cost_ij(const float* __restrict__ a,
                                         const float* __restrict__ b) {
#pragma clang fp contract(off)
  float s = 0.0f;
#pragma unroll
  for (int p = 0; p < PP; ++p) {
    float dx = a[2 * p]     - b[2 * p];
    float dy = a[2 * p + 1] - b[2 * p + 1];
    s += sqrtf(dx * dx + dy * dy);
  }
  return s / 20.0f;
}

// Quantized cost: c * 2^25 is an exact integer for all entries in [2^-2, 2^3]
// (fp32 ulp <= 2^-25 there). Computed in double => exact product + exact cast.
__global__ void cost_kernel(const float* __restrict__ pred,
                            const float* __restrict__ gt,
                            int* __restrict__ ci) {
  int id = blockIdx.x * blockDim.x + threadIdx.x;  // 0 .. NN*NN-1
  int i = id >> 10;
  int j = id & (NN - 1);
  float c = cost_ij(pred + i * 40, gt + j * 40);
  ci[id] = (int)((double)c * SCALE_D);
}

// ---------- init auction state ----------
__global__ void init_kernel(int* __restrict__ u, int* __restrict__ r4c,
                            int* __restrict__ c4r,
                            unsigned long long* __restrict__ bids) {
  const int t = blockIdx.x * blockDim.x + threadIdx.x;  // 1024
  u[t] = 0;
  r4c[t] = -1;
  c4r[t] = -1;
  bids[t] = 0ull;
}

// ---------- column minima -> initial prices v ----------
__global__ void colmin_kernel(const int* __restrict__ ci,
                              int* __restrict__ v) {
  int j = blockIdx.x * blockDim.x + threadIdx.x;  // 1024 threads total
  int mv = ci[j];
#pragma unroll 8
  for (int i = 1; i < NN; ++i) {
    int c = ci[i * NN + j];
    if (c < mv) mv = c;
  }
  v[j] = mv;
}

// ---------- auction bid: one wave per free row ----------
// Computes (m1, m2, j1) of reduced costs c - v; posts packed bid
// (delta<<32 | row+1) to column j1 via atomicMax (max delta wins).
__global__ __launch_bounds__(64) void bid_kernel(
    const int* __restrict__ ci, const int* __restrict__ v,
    const int* __restrict__ c4r, int* __restrict__ bidm2,
    unsigned long long* __restrict__ bids) {
  const int row = blockIdx.x;
  if (c4r[row] >= 0) return;  // assigned rows don't bid (uniform)
  const int lane = threadIdx.x;
  const int* cr = ci + (size_t)row * NN + lane * LPC;
  const int* vr = v + lane * LPC;
  int4 ca = ((const int4*)cr)[0], cb = ((const int4*)cr)[1],
       cc = ((const int4*)cr)[2], cd = ((const int4*)cr)[3];
  int4 va = ((const int4*)vr)[0], vb = ((const int4*)vr)[1],
       vc = ((const int4*)vr)[2], vd = ((const int4*)vr)[3];
  int c[LPC] = {ca.x, ca.y, ca.z, ca.w, cb.x, cb.y, cb.z, cb.w,
                cc.x, cc.y, cc.z, cc.w, cd.x, cd.y, cd.z, cd.w};
  int vv[LPC] = {va.x, va.y, va.z, va.w, vb.x, vb.y, vb.z, vb.w,
                 vc.x, vc.y, vc.z, vc.w, vd.x, vd.y, vd.z, vd.w};
  int m1 = IMAX, m2 = IMAX, c1 = IMAX;
#pragma unroll
  for (int q = 0; q < LPC; ++q) {
    const int d = c[q] - vv[q];
    if (d < m1) { m2 = m1; m1 = d; c1 = lane * LPC + q; }
    else if (d < m2) m2 = d;
  }
#pragma unroll
  for (int m = 1; m < 64; m <<= 1) {
    const int pm1 = __shfl_xor(m1, m);
    const int pm2 = __shfl_xor(m2, m);
    const int pc1 = __shfl_xor(c1, m);
    const int hi = (m1 > pm1) ? m1 : pm1;
    const int lo2 = (m2 < pm2) ? m2 : pm2;
    if (pm1 < m1 || (pm1 == m1 && pc1 < c1)) { m1 = pm1; c1 = pc1; }
    m2 = (hi < lo2) ? hi : lo2;
  }
  if (lane == 0) {
    bidm2[row] = m2;
    const unsigned long long pk =
        ((unsigned long long)(unsigned)(m2 - m1) << 32) |
        (unsigned long long)(unsigned)(row + 1);
    atomicMax(&bids[c1], pk);
  }
}

// ---------- auction resolve: one thread per column ----------
// Winner takes the column: u[w]=m2_w, v[j]=c[w][j]-m2_w (monotone decrease),
// old occupant displaced to free. Preserves assigned-row dual feasibility:
// after the update, c[w][j'] - v[j'] >= m2_w = u[w] for all j' (second-min
// property), with equality at j. Winners/displaced are disjoint across j.
__global__ void resolve_kernel(const int* __restrict__ ci, int* __restrict__ v,
                               int* __restrict__ u, int* __restrict__ r4c,
                               int* __restrict__ c4r,
                               const int* __restrict__ bidm2,
                               unsigned long long* __restrict__ bids) {
  const int j = blockIdx.x * blockDim.x + threadIdx.x;  // 1024
  const unsigned long long b = bids[j];
  if (b == 0ull) return;
  bids[j] = 0ull;
  const int row = (int)(b & 0xffffffffull) - 1;
  const int m2 = bidm2[row];
  const int disp = r4c[j];
  r4c[j] = row;
  c4r[row] = j;
  if (disp >= 0) c4r[disp] = -1;
  v[j] = ci[(size_t)row * NN + j] - m2;
  u[row] = m2;
}

// ---------- wave64 min via DPP (LLVM AtomicOptimizer wave64 pattern) -------
__device__ __forceinline__ int wave_min_bcast(int x) {
  int t;
  t = __builtin_amdgcn_update_dpp(IMAX, x, 0x111, 0xf, 0xf, false);  // row_shr:1
  x = (t < x) ? t : x;
  t = __builtin_amdgcn_update_dpp(IMAX, x, 0x112, 0xf, 0xf, false);  // row_shr:2
  x = (t < x) ? t : x;
  t = __builtin_amdgcn_update_dpp(IMAX, x, 0x114, 0xf, 0xf, false);  // row_shr:4
  x = (t < x) ? t : x;
  t = __builtin_amdgcn_update_dpp(IMAX, x, 0x118, 0xf, 0xf, false);  // row_shr:8
  x = (t < x) ? t : x;
  t = __builtin_amdgcn_update_dpp(IMAX, x, 0x142, 0xf, 0xf, false);  // row_bcast:15
  x = (t < x) ? t : x;
  t = __builtin_amdgcn_update_dpp(IMAX, x, 0x143, 0xf, 0xf, false);  // row_bcast:31
  x = (t < x) ? t : x;
  return __builtin_amdgcn_readlane(x, 63);
}

// ---------- single-wave finisher: residual ARR + Dijkstra (R7-proven) -----
__global__ __launch_bounds__(64) void lap_kernel(
    const float* __restrict__ gt, const int* __restrict__ ci,
    const int* __restrict__ v_g, const int* __restrict__ u_g,
    const int* __restrict__ r4c_g, const int* __restrict__ c4r_g,
    float* __restrict__ out) {
  const int lane = threadIdx.x;

  __shared__ int u_s[NN];
  __shared__ int row4col_s[NN];
  __shared__ int col4row_s[NN];
  __shared__ int path_s[NN];
  __shared__ int queue_s[NN + ARR_CAP2];

  int nv_r[LPC];  // NEGATED v duals for owned cols
  int sh_r[LPC];  // Dijkstra labels
  int kq_r[LPC];  // argmin key: == sh_r active, IMAX when settled
  int pa_r[LPC];  // predecessor row per owned col
  int rc_r[LPC];  // register mirror of row4col for owned cols

  // ---- L2 priming: touch every 64B of the 4 MB cost matrix ----
  {
    const char* base = (const char*)ci;
    int ax = 0, ay = 0, az = 0, aw = 0;
    for (int it = 0; it < 1024; it += 8) {
#pragma unroll
      for (int uu = 0; uu < 8; ++uu) {
        const int4 tv =
            *(const int4*)(base + ((size_t)(it + uu) * 64 + lane) * 64);
        ax ^= tv.x; ay ^= tv.y; az ^= tv.z; aw ^= tv.w;
      }
    }
    asm volatile("" :: "v"(ax), "v"(ay), "v"(az), "v"(aw));
  }

  // ---- load auction state ----
#pragma unroll
  for (int q = 0; q < LPC; ++q) {
    const int j = lane * LPC + q;
    u_s[j] = u_g[j];
    row4col_s[j] = r4c_g[j];
    col4row_s[j] = c4r_g[j];
    nv_r[q] = -v_g[j];
  }
  __syncthreads();
  if (lane == 0) {
    int n = 0;
    for (int i = 0; i < NN; ++i)
      if (col4row_s[i] < 0) queue_s[n++] = i;
    path_s[0] = n;
  }
  __syncthreads();
  int head = 0;
  int tail = path_s[0];  // uniform
  __syncthreads();

  // ---- residual continuous ARR (JV87 queue), R7 structure ----
  for (int step = 0; step < ARR_CAP2 && head < tail; ++step) {
    const int i = queue_s[head];  // uniform read
    ++head;
    const int* cr = ci + (size_t)i * NN + lane * LPC;
    int4 ca = ((const int4*)cr)[0], cb = ((const int4*)cr)[1],
         cc = ((const int4*)cr)[2], cd = ((const int4*)cr)[3];
    int c[LPC] = {ca.x, ca.y, ca.z, ca.w, cb.x, cb.y, cb.z, cb.w,
                  cc.x, cc.y, cc.z, cc.w, cd.x, cd.y, cd.z, cd.w};
    int m1 = IMAX, m2 = IMAX, c1 = 0;
#pragma unroll
    for (int q = 0; q < LPC; ++q) {
      const int d = c[q] + nv_r[q];
      if (d < m1) { m2 = m1; m1 = d; c1 = q; }
      else if (d < m2) m2 = d;
    }
    const int m1g = wave_min_bcast(m1);
    const unsigned long long ball = __ballot(m1 == m1g);
    const int wl = __ffsll(ball) - 1;
    const int cand = (lane == wl) ? m2 : m1;
    const int m2g = wave_min_bcast(cand);
    const int j1 = (wl << 4) | __builtin_amdgcn_readlane(c1, wl);
    const int delta = m2g - m1g;  // >= 0
    if (lane == wl && delta > 0) {
#pragma unroll
      for (int q = 0; q < LPC; ++q)
        if (q == (j1 & 15)) nv_r[q] += delta;
    }
    const int k = row4col_s[j1];  // pre-write value
    __syncthreads();
    if (lane == 0) {
      u_s[i] = m2g;
      row4col_s[j1] = i;
      col4row_s[i] = j1;
      if (k >= 0) {
        col4row_s[k] = -1;
        queue_s[tail] = k;
      }
    }
    if (k >= 0) ++tail;  // uniform
    __syncthreads();
  }

#pragma unroll
  for (int q = 0; q < LPC; ++q) rc_r[q] = row4col_s[lane * LPC + q];
  __syncthreads();

  // ---- Dijkstra augmentation for residual rows (R7 verbatim) ----
  const int nfree = tail - head;
  for (int fi = 0; fi < nfree; ++fi) {
    const int r = queue_s[head + fi];  // uniform
#pragma unroll
    for (int q = 0; q < LPC; ++q) { sh_r[q] = IMAX; kq_r[q] = IMAX; }
    int i = r;
    int mv = 0;
    int A = __builtin_amdgcn_readfirstlane(-u_s[r]);
    int sink;
    while (true) {
      const int* cr = ci + (size_t)i * NN + lane * LPC;
      int4 ca = ((const int4*)cr)[0], cb = ((const int4*)cr)[1],
           cc = ((const int4*)cr)[2], cd = ((const int4*)cr)[3];
      int c[LPC] = {ca.x, ca.y, ca.z, ca.w, cb.x, cb.y, cb.z, cb.w,
                    cc.x, cc.y, cc.z, cc.w, cd.x, cd.y, cd.z, cd.w};
#pragma unroll
      for (int q = 0; q < LPC; ++q) {
        const int d = A + c[q] + nv_r[q];
        const bool upd = d < sh_r[q];
        sh_r[q] = upd ? d : sh_r[q];
        kq_r[q] = upd ? d : kq_r[q];
        pa_r[q] = upd ? i : pa_r[q];
      }
      int t1k[8], t1e[8], t1r[8];
#pragma unroll
      for (int q = 0; q < 8; ++q) {
        const bool b = kq_r[2 * q + 1] < kq_r[2 * q];
        t1k[q] = b ? kq_r[2 * q + 1] : kq_r[2 * q];
        t1e[q] = b ? 2 * q + 1 : 2 * q;
        t1r[q] = b ? rc_r[2 * q + 1] : rc_r[2 * q];
      }
      int t2k[4], t2e[4], t2r[4];
#pragma unroll
      for (int q = 0; q < 4; ++q) {
        const bool b = t1k[2 * q + 1] < t1k[2 * q];
        t2k[q] = b ? t1k[2 * q + 1] : t1k[2 * q];
        t2e[q] = b ? t1e[2 * q + 1] : t1e[2 * q];
        t2r[q] = b ? t1r[2 * q + 1] : t1r[2 * q];
      }
      int t3k[2], t3e[2], t3r[2];
#pragma unroll
      for (int q = 0; q < 2; ++q) {
        const bool b = t2k[2 * q + 1] < t2k[2 * q];
        t3k[q] = b ? t2k[2 * q + 1] : t2k[2 * q];
        t3e[q] = b ? t2e[2 * q + 1] : t2e[2 * q];
        t3r[q] = b ? t2r[2 * q + 1] : t2r[2 * q];
      }
      const bool b0 = t3k[1] < t3k[0];
      const int bs = b0 ? t3k[1] : t3k[0];
      const int bq = b0 ? t3e[1] : t3e[0];
      const int brc = b0 ? t3r[1] : t3r[0];
      const int minkey = wave_min_bcast(bs);
      const unsigned long long ball = __ballot(bs == minkey);
      const int wl = __ffsll(ball) - 1;
      const int kcol = (wl << 4) | __builtin_amdgcn_readlane(bq, wl);
      const int krc = __builtin_amdgcn_readlane(brc, wl);
      mv = minkey;
      if (krc < 0) { sink = kcol; break; }
      if (lane == (kcol >> 4)) {
#pragma unroll
        for (int q = 0; q < LPC; ++q)
          if (q == (kcol & 15)) kq_r[q] = IMAX;
      }
      i = krc;
      A = __builtin_amdgcn_readfirstlane(mv - u_s[i]);
    }
#pragma unroll
    for (int q = 0; q < LPC; ++q) {
      if (kq_r[q] == IMAX && sh_r[q] != IMAX) {
        const int delta = mv - sh_r[q];
        const int i2 = rc_r[q];
        if (i2 >= 0) u_s[i2] += delta;
        nv_r[q] += delta;
      }
      path_s[lane * LPC + q] = pa_r[q];
    }
    if (lane == 0) u_s[r] += mv;
    __syncthreads();
    if (lane == 0) {
      int j = sink;
      while (true) {
        const int i2 = path_s[j];
        row4col_s[j] = i2;
        const int jn = col4row_s[i2];
        col4row_s[i2] = j;
        j = jn;
        if (i2 == r) break;
      }
    }
    __syncthreads();
#pragma unroll
    for (int q = 0; q < LPC; ++q) rc_r[q] = row4col_s[lane * LPC + q];
  }
  __syncthreads();

  // ---------- outputs: 16 rows per lane ----------
#pragma unroll
  for (int q = 0; q < LPC; ++q) {
    const int row = lane * LPC + q;
    const int col = col4row_s[row];
    const float4* g4 = (const float4*)(gt + (size_t)col * 40);
    float4* o4 = (float4*)(out + (size_t)row * 40);
#pragma unroll
    for (int w = 0; w < 10; ++w) o4[w] = g4[w];
    const float cf = (float)ci[(size_t)row * NN + col] * INV_SCALE_F;
    out[NN * 40 + row] = expf(-cf);
  }
}

extern "C" void kernel_launch(void* const* d_in, const int* in_sizes, int n_in,
                              void* d_out, int out_size, void* d_ws,
                              size_t ws_size, hipStream_t stream) {
  const float* pred = (const float*)d_in[0];
  const float* gt = (const float*)d_in[1];
  float* out = (float*)d_out;
  int* ci = (int*)d_ws;  // 4 MB quantized cost

  // scratch in d_out's head (fully overwritten by lap epilogue):
  int* v_g = (int*)out;                          // [0, 1024)
  int* u_g = (int*)out + NN;                     // [1024, 2048)
  int* r4c = (int*)out + 2 * NN;                 // [2048, 3072)
  int* c4r = (int*)out + 3 * NN;                 // [3072, 4096)
  int* bidm2 = (int*)out + 4 * NN;               // [4096, 5120)
  unsigned long long* bids =
      (unsigned long long*)((int*)out + 5 * NN); // byte 20480, 8B-aligned

  cost_kernel<<<NN * NN / 256, 256, 0, stream>>>(pred, gt, ci);
  init_kernel<<<NN / 256, 256, 0, stream>>>(u_g, r4c, c4r, bids);
  colmin_kernel<<<NN / 256, 256, 0, stream>>>(ci, v_g);
  for (int r = 0; r < NROUNDS; ++r) {
    bid_kernel<<<NN, 64, 0, stream>>>(ci, v_g, c4r, bidm2, bids);
    resolve_kernel<<<NN / 256, 256, 0, stream>>>(ci, v_g, u_g, r4c, c4r,
                                                 bidm2, bids);
  }
  lap_kernel<<<1, 64, 0, stream>>>(gt, ci, v_g, u_g, r4c, c4r, out);
}